// Round 1
// baseline (2093.601 us; speedup 1.0000x reference)
//
#include <hip/hip_runtime.h>
#include <hip/hip_bf16.h>

// Problem: grouped experts FFN. E=8, C=2048, D=2048, F=8192, G=1.
// y[e] = GELU(x[e] @ W1[e] + b1[e]) @ W2[e] + b2[e]
// Strategy: bf16 MFMA (threshold allows), fp32 accumulate.
//   pass 1: convert x -> bf16; transpose-convert W1 -> [F][D] bf16, W2 -> [D][F] bf16
//           (both GEMM operands K-contiguous => ds_read_b128 fragments)
//   pass 2: GEMM1 (M=C,N=F,K=D) + bias + exact GELU -> h bf16 (ws)
//   pass 3: GEMM2 (M=C,N=D,K=F) + bias -> fp32 out

#define E_ 8
#define C_ 2048
#define D_ 2048
#define F_ 8192

typedef short bf16x8 __attribute__((ext_vector_type(8)));   // 8 bf16 in 4 VGPRs
typedef float f32x4  __attribute__((ext_vector_type(4)));

__device__ inline unsigned short f2bf(float f) {
    // round-to-nearest-even bf16
    unsigned u = __float_as_uint(f);
    u += 0x7fffu + ((u >> 16) & 1u);
    return (unsigned short)(u >> 16);
}

__device__ inline void gload_lds16(const void* g, void* l) {
    __builtin_amdgcn_global_load_lds(
        (const __attribute__((address_space(1))) void*)g,
        (__attribute__((address_space(3))) void*)l, 16, 0, 0);
}

// ---------------------------------------------------------------- cvt x ----
__global__ __launch_bounds__(256) void cvt_kernel(
    const float* __restrict__ in, unsigned short* __restrict__ out, long n4)
{
    long i = (long)blockIdx.x * 256 + threadIdx.x;
    if (i >= n4) return;
    float4 v = ((const float4*)in)[i];
    union { unsigned short u[4]; uint2 q; } r;
    r.u[0] = f2bf(v.x); r.u[1] = f2bf(v.y); r.u[2] = f2bf(v.z); r.u[3] = f2bf(v.w);
    ((uint2*)out)[i] = r.q;
}

// --------------------------------------------- transpose + cvt (weights) ----
// per expert: in fp32 [R][Cc] -> out bf16 [Cc][R]
__global__ __launch_bounds__(256) void transpose_cvt(
    const float* __restrict__ in, unsigned short* __restrict__ out,
    int R, int Cc, int RT, int CT)
{
    __shared__ float lds[64][65];   // +1 pad: phase-2 column reads 2-way max
    int bx = blockIdx.x;
    int e  = bx / (RT * CT);
    int rem = bx % (RT * CT);
    int rt = rem / CT, ct = rem % CT;
    const float* ine = in + (long)e * R * Cc;
    unsigned short* oute = out + (long)e * R * Cc;
    long r0 = (long)rt * 64, c0 = (long)ct * 64;
    int t = threadIdx.x;

    int lr = t >> 4, lc = t & 15;
#pragma unroll
    for (int ii = 0; ii < 4; ++ii) {
        int r = lr + ii * 16;
        float4 v = *(const float4*)(ine + (r0 + r) * Cc + c0 + lc * 4);
        lds[r][lc * 4 + 0] = v.x; lds[r][lc * 4 + 1] = v.y;
        lds[r][lc * 4 + 2] = v.z; lds[r][lc * 4 + 3] = v.w;
    }
    __syncthreads();

    int nl = t >> 3, kv = t & 7;
#pragma unroll
    for (int ii = 0; ii < 2; ++ii) {
        int n = nl + ii * 32;
        union { unsigned short u[8]; uint4 q; } r;
#pragma unroll
        for (int j = 0; j < 8; ++j) r.u[j] = f2bf(lds[kv * 8 + j][n]);
        *(uint4*)(oute + (c0 + n) * R + r0 + kv * 8) = r.q;  // 16B coalesced
    }
}

// ------------------------------------------------------------------ GEMM ----
// C[e][M][N] = A[e][M][K] * Bt[e][N][K]^T (+bias[e][N]) (opt GELU)
// A rows K-contiguous, Bt rows K-contiguous. M,N mult of 128, K mult of 64.
template <bool GELU, bool OUT_BF16>
__global__ __launch_bounds__(256) void gemm_bt(
    const unsigned short* __restrict__ A,
    const unsigned short* __restrict__ Bt,
    const float* __restrict__ bias,
    void* __restrict__ Cout,
    int M, int N, int K,
    long strideAe, long strideBe, long strideCe, int biasStride)
{
    constexpr int BM = 128, BN = 128, BK = 64;
    __shared__ unsigned short sA[2][BM * BK];   // 16 KB each buf
    __shared__ unsigned short sB[2][BN * BK];

    int MT = M / BM, NT = N / BN;
    int bx = blockIdx.x;
    int e   = bx / (MT * NT);
    int rem = bx % (MT * NT);
    int mt = rem / NT, nt = rem % NT;

    const unsigned short* Ae = A  + (long)e * strideAe + (long)mt * BM * K;
    const unsigned short* Be = Bt + (long)e * strideBe + (long)nt * BN * K;

    int tid  = threadIdx.x;
    int lane = tid & 63;
    int wid  = tid >> 6;
    int wr = wid >> 1, wc = wid & 1;    // 2x2 wave grid, each wave 64x64 out

    f32x4 acc[4][4] = {};

    auto stage = [&](int buf, int kt) {
        long k0 = (long)kt * BK;
#pragma unroll
        for (int it = 0; it < 4; ++it) {
            int g   = tid + it * 256;   // 16B granule id, 1024 per tile
            int row = g >> 3;
            int col = g & 7;            // linear (no swizzle at 2-phase; T2 null here)
            gload_lds16(Ae + (long)row * K + k0 + col * 8, &sA[buf][g * 8]);
            gload_lds16(Be + (long)row * K + k0 + col * 8, &sB[buf][g * 8]);
        }
    };

    auto compute = [&](int buf) {
#pragma unroll
        for (int ks = 0; ks < 2; ++ks) {
            bf16x8 af[4], bf[4];
#pragma unroll
            for (int mi = 0; mi < 4; ++mi) {
                int row = wr * 64 + mi * 16 + (lane & 15);
                int off = row * 128 + ks * 64 + (lane >> 4) * 16;   // bytes
                af[mi] = *(const bf16x8*)((const char*)&sA[buf][0] + off);
            }
#pragma unroll
            for (int ni = 0; ni < 4; ++ni) {
                int row = wc * 64 + ni * 16 + (lane & 15);
                int off = row * 128 + ks * 64 + (lane >> 4) * 16;
                bf[ni] = *(const bf16x8*)((const char*)&sB[buf][0] + off);
            }
#pragma unroll
            for (int mi = 0; mi < 4; ++mi)
#pragma unroll
                for (int ni = 0; ni < 4; ++ni)
                    acc[mi][ni] = __builtin_amdgcn_mfma_f32_16x16x32_bf16(
                        af[mi], bf[ni], acc[mi][ni], 0, 0, 0);
        }
    };

    int KT = K / BK;
    stage(0, 0);
    __syncthreads();
    for (int kt = 0; kt < KT; ++kt) {
        int buf = kt & 1;
        if (kt + 1 < KT) stage(buf ^ 1, kt + 1);
        compute(buf);
        __syncthreads();    // drains vmcnt(0): next buf ready, cur buf free
    }

    // epilogue: C/D layout col=lane&15, row=(lane>>4)*4+j  [verified mapping]
    const float* be = bias + (long)e * biasStride;
    long cBase = (long)e * strideCe + (long)mt * BM * N + nt * BN;
#pragma unroll
    for (int mi = 0; mi < 4; ++mi) {
#pragma unroll
        for (int ni = 0; ni < 4; ++ni) {
            int col = wc * 64 + ni * 16 + (lane & 15);
            float bv = be[nt * BN + col];
#pragma unroll
            for (int j = 0; j < 4; ++j) {
                int rowl = wr * 64 + mi * 16 + (lane >> 4) * 4 + j;
                float v = acc[mi][ni][j] + bv;
                if (GELU) v = 0.5f * v * (1.0f + erff(v * 0.70710678118654752f));
                long idx = cBase + (long)rowl * N + col;
                if (OUT_BF16) ((unsigned short*)Cout)[idx] = f2bf(v);
                else          ((float*)Cout)[idx] = v;
            }
        }
    }
}

// ------------------------------------------------------------------ host ----
extern "C" void kernel_launch(void* const* d_in, const int* in_sizes, int n_in,
                              void* d_out, int out_size, void* d_ws, size_t ws_size,
                              hipStream_t stream)
{
    const float* x  = (const float*)d_in[0];
    const float* w1 = (const float*)d_in[1];
    const float* b1 = (const float*)d_in[2];
    const float* w2 = (const float*)d_in[3];
    const float* b2 = (const float*)d_in[4];
    float* out = (float*)d_out;

    const long CD = (long)C_ * D_;      // 4.19M
    const long DF = (long)D_ * F_;      // 16.8M
    const long CF = (long)C_ * F_;      // 16.8M
    const long perExpertElems = CD + 2 * DF + CF;   // bf16 elems, ~109MB
    long ceMax = (long)(ws_size / ((size_t)perExpertElems * 2));
    int CE = (int)(ceMax < 1 ? 1 : (ceMax > E_ ? E_ : ceMax));

    unsigned short* xb  = (unsigned short*)d_ws;
    unsigned short* w1t = xb  + (long)CE * CD;   // [e][F][D]
    unsigned short* w2t = w1t + (long)CE * DF;   // [e][D][F]
    unsigned short* h   = w2t + (long)CE * DF;   // [e][C][F]

    for (int e0 = 0; e0 < E_; e0 += CE) {
        int ce = (E_ - e0) < CE ? (E_ - e0) : CE;

        long n4 = (long)ce * CD / 4;
        cvt_kernel<<<(int)((n4 + 255) / 256), 256, 0, stream>>>(
            x + (long)e0 * CD, xb, n4);

        transpose_cvt<<<ce * (D_ / 64) * (F_ / 64), 256, 0, stream>>>(
            w1 + (long)e0 * DF, w1t, D_, F_, D_ / 64, F_ / 64);

        transpose_cvt<<<ce * (F_ / 64) * (D_ / 64), 256, 0, stream>>>(
            w2 + (long)e0 * DF, w2t, F_, D_, F_ / 64, D_ / 64);

        gemm_bt<true, true><<<ce * (C_ / 128) * (F_ / 128), 256, 0, stream>>>(
            xb, w1t, b1 + (long)e0 * F_, (void*)h,
            C_, F_, D_, CD, DF, CF, F_);

        gemm_bt<false, false><<<ce * (C_ / 128) * (D_ / 128), 256, 0, stream>>>(
            h, w2t, b2 + (long)e0 * D_, (void*)(out + (long)e0 * CD),
            C_, D_, F_, CF, DF, CD, D_);
    }
}

// Round 2
// 1620.745 us; speedup vs baseline: 1.2918x; 1.2918x over previous
//
#include <hip/hip_runtime.h>
#include <hip/hip_bf16.h>

// Grouped experts FFN. E=8, C=2048, D=2048, F=8192, G=1.
// y[e] = GELU(x[e] @ W1[e] + b1[e]) @ W2[e] + b2[e]
// bf16 MFMA, fp32 accumulate.
// R2: m97-proven GEMM structure — single-buffered BK=64 (32KB LDS, was 64KB
//     dbuf -> occupancy 2->4 blocks/CU) + both-sides XOR swizzle
//     (col ^= row&7 on 16B granules) to kill the 16-way ds_read_b128 conflict.

#define E_ 8
#define C_ 2048
#define D_ 2048
#define F_ 8192

typedef short bf16x8 __attribute__((ext_vector_type(8)));
typedef float f32x4  __attribute__((ext_vector_type(4)));

__device__ inline unsigned short f2bf(float f) {
    unsigned u = __float_as_uint(f);
    u += 0x7fffu + ((u >> 16) & 1u);
    return (unsigned short)(u >> 16);
}

__device__ inline void gload_lds16(const void* g, void* l) {
    __builtin_amdgcn_global_load_lds(
        (const __attribute__((address_space(1))) void*)g,
        (__attribute__((address_space(3))) void*)l, 16, 0, 0);
}

// ---------------------------------------------------------------- cvt x ----
__global__ __launch_bounds__(256) void cvt_kernel(
    const float* __restrict__ in, unsigned short* __restrict__ out, long n4)
{
    long i = (long)blockIdx.x * 256 + threadIdx.x;
    if (i >= n4) return;
    float4 v = ((const float4*)in)[i];
    union { unsigned short u[4]; uint2 q; } r;
    r.u[0] = f2bf(v.x); r.u[1] = f2bf(v.y); r.u[2] = f2bf(v.z); r.u[3] = f2bf(v.w);
    ((uint2*)out)[i] = r.q;
}

// --------------------------------------------- transpose + cvt (weights) ----
__global__ __launch_bounds__(256) void transpose_cvt(
    const float* __restrict__ in, unsigned short* __restrict__ out,
    int R, int Cc, int RT, int CT)
{
    __shared__ float lds[64][65];
    int bx = blockIdx.x;
    int e  = bx / (RT * CT);
    int rem = bx % (RT * CT);
    int rt = rem / CT, ct = rem % CT;
    const float* ine = in + (long)e * R * Cc;
    unsigned short* oute = out + (long)e * R * Cc;
    long r0 = (long)rt * 64, c0 = (long)ct * 64;
    int t = threadIdx.x;

    int lr = t >> 4, lc = t & 15;
#pragma unroll
    for (int ii = 0; ii < 4; ++ii) {
        int r = lr + ii * 16;
        float4 v = *(const float4*)(ine + (r0 + r) * Cc + c0 + lc * 4);
        lds[r][lc * 4 + 0] = v.x; lds[r][lc * 4 + 1] = v.y;
        lds[r][lc * 4 + 2] = v.z; lds[r][lc * 4 + 3] = v.w;
    }
    __syncthreads();

    int nl = t >> 3, kv = t & 7;
#pragma unroll
    for (int ii = 0; ii < 2; ++ii) {
        int n = nl + ii * 32;
        union { unsigned short u[8]; uint4 q; } r;
#pragma unroll
        for (int j = 0; j < 8; ++j) r.u[j] = f2bf(lds[kv * 8 + j][n]);
        *(uint4*)(oute + (c0 + n) * R + r0 + kv * 8) = r.q;
    }
}

// ------------------------------------------------------------------ GEMM ----
// C[e][M][N] = A[e][M][K] * Bt[e][N][K]^T (+bias[e][N]) (opt GELU)
// m97 structure: 128x128 tile, BK=64, single LDS buffer, 2 barriers/K-step.
// LDS layout: [row][col16B] with col16B granules XOR-swizzled by (row&7).
// Staging pre-applies the inverse (same) swizzle to the GLOBAL source so the
// linear global_load_lds destination ends up holding the swizzled layout.
template <bool GELU, bool OUT_BF16>
__global__ __launch_bounds__(256) void gemm_bt(
    const unsigned short* __restrict__ A,
    const unsigned short* __restrict__ Bt,
    const float* __restrict__ bias,
    void* __restrict__ Cout,
    int M, int N, int K,
    long strideAe, long strideBe, long strideCe, int biasStride)
{
    constexpr int BM = 128, BN = 128, BK = 64;
    __shared__ unsigned short sA[BM * BK];   // 16 KB
    __shared__ unsigned short sB[BN * BK];   // 16 KB

    int MT = M / BM, NT = N / BN;
    int bx = blockIdx.x;
    int e   = bx / (MT * NT);
    int rem = bx % (MT * NT);
    int mt = rem / NT, nt = rem % NT;

    const unsigned short* Ae = A  + (long)e * strideAe + (long)mt * BM * K;
    const unsigned short* Be = Bt + (long)e * strideBe + (long)nt * BN * K;

    int tid  = threadIdx.x;
    int lane = tid & 63;
    int wid  = tid >> 6;
    int wr = wid >> 1, wc = wid & 1;    // 2x2 wave grid, each wave 64x64 out

    f32x4 acc[4][4] = {};

    auto stage = [&](int kt) {
        long k0 = (long)kt * BK;
#pragma unroll
        for (int it = 0; it < 4; ++it) {
            int g    = tid + it * 256;       // 16B granule id, 1024/tile
            int row  = g >> 3;
            int col  = g & 7;
            int scol = col ^ (row & 7);      // pre-swizzled global source
            gload_lds16(Ae + (long)row * K + k0 + scol * 8, &sA[g * 8]);
            gload_lds16(Be + (long)row * K + k0 + scol * 8, &sB[g * 8]);
        }
    };

    auto compute = [&]() {
#pragma unroll
        for (int ks = 0; ks < 2; ++ks) {
            bf16x8 af[4], bf[4];
#pragma unroll
            for (int mi = 0; mi < 4; ++mi) {
                int row = wr * 64 + mi * 16 + (lane & 15);
                int c   = ks * 64 + (lane >> 4) * 16;      // byte col
                int off = row * 128 + (c ^ ((row & 7) << 4));
                af[mi] = *(const bf16x8*)((const char*)sA + off);
            }
#pragma unroll
            for (int ni = 0; ni < 4; ++ni) {
                int row = wc * 64 + ni * 16 + (lane & 15);
                int c   = ks * 64 + (lane >> 4) * 16;
                int off = row * 128 + (c ^ ((row & 7) << 4));
                bf[ni] = *(const bf16x8*)((const char*)sB + off);
            }
#pragma unroll
            for (int mi = 0; mi < 4; ++mi)
#pragma unroll
                for (int ni = 0; ni < 4; ++ni)
                    acc[mi][ni] = __builtin_amdgcn_mfma_f32_16x16x32_bf16(
                        af[mi], bf[ni], acc[mi][ni], 0, 0, 0);
        }
    };

    int KT = K / BK;
    for (int kt = 0; kt < KT; ++kt) {
        stage(kt);
        __syncthreads();   // vmcnt(0) drain: tile staged
        compute();
        __syncthreads();   // all reads done before next overwrite
    }

    // epilogue: C/D layout col=lane&15, row=(lane>>4)*4+j
    const float* be = bias + (long)e * biasStride;
    long cBase = (long)e * strideCe + (long)mt * BM * N + nt * BN;
#pragma unroll
    for (int mi = 0; mi < 4; ++mi) {
#pragma unroll
        for (int ni = 0; ni < 4; ++ni) {
            int col = wc * 64 + ni * 16 + (lane & 15);
            float bv = be[nt * BN + col];
#pragma unroll
            for (int j = 0; j < 4; ++j) {
                int rowl = wr * 64 + mi * 16 + (lane >> 4) * 4 + j;
                float v = acc[mi][ni][j] + bv;
                if (GELU) v = 0.5f * v * (1.0f + erff(v * 0.70710678118654752f));
                long idx = cBase + (long)rowl * N + col;
                if (OUT_BF16) ((unsigned short*)Cout)[idx] = f2bf(v);
                else          ((float*)Cout)[idx] = v;
            }
        }
    }
}

// ------------------------------------------------------------------ host ----
extern "C" void kernel_launch(void* const* d_in, const int* in_sizes, int n_in,
                              void* d_out, int out_size, void* d_ws, size_t ws_size,
                              hipStream_t stream)
{
    const float* x  = (const float*)d_in[0];
    const float* w1 = (const float*)d_in[1];
    const float* b1 = (const float*)d_in[2];
    const float* w2 = (const float*)d_in[3];
    const float* b2 = (const float*)d_in[4];
    float* out = (float*)d_out;

    const long CD = (long)C_ * D_;
    const long DF = (long)D_ * F_;
    const long CF = (long)C_ * F_;
    const long perExpertElems = CD + 2 * DF + CF;
    long ceMax = (long)(ws_size / ((size_t)perExpertElems * 2));
    int CE = (int)(ceMax < 1 ? 1 : (ceMax > E_ ? E_ : ceMax));

    unsigned short* xb  = (unsigned short*)d_ws;
    unsigned short* w1t = xb  + (long)CE * CD;   // [e][F][D]
    unsigned short* w2t = w1t + (long)CE * DF;   // [e][D][F]
    unsigned short* h   = w2t + (long)CE * DF;   // [e][C][F]

    for (int e0 = 0; e0 < E_; e0 += CE) {
        int ce = (E_ - e0) < CE ? (E_ - e0) : CE;

        long n4 = (long)ce * CD / 4;
        cvt_kernel<<<(int)((n4 + 255) / 256), 256, 0, stream>>>(
            x + (long)e0 * CD, xb, n4);

        transpose_cvt<<<ce * (D_ / 64) * (F_ / 64), 256, 0, stream>>>(
            w1 + (long)e0 * DF, w1t, D_, F_, D_ / 64, F_ / 64);

        transpose_cvt<<<ce * (F_ / 64) * (D_ / 64), 256, 0, stream>>>(
            w2 + (long)e0 * DF, w2t, F_, D_, F_ / 64, D_ / 64);

        gemm_bt<true, true><<<ce * (C_ / 128) * (F_ / 128), 256, 0, stream>>>(
            xb, w1t, b1 + (long)e0 * F_, (void*)h,
            C_, F_, D_, CD, DF, CF, F_);

        gemm_bt<false, false><<<ce * (C_ / 128) * (D_ / 128), 256, 0, stream>>>(
            h, w2t, b2 + (long)e0 * D_, (void*)(out + (long)e0 * CD),
            C_, D_, F_, CF, DF, CD, D_);
    }
}

// Round 3
// 1526.733 us; speedup vs baseline: 1.3713x; 1.0616x over previous
//
#include <hip/hip_runtime.h>
#include <hip/hip_bf16.h>

// Grouped experts FFN. E=8, C=2048, D=2048, F=8192.
// y[e] = GELU(x[e] @ W1[e] + b1[e]) @ W2[e] + b2[e]
// R3: 256x256 8-phase counted-vmcnt GEMM (T2+T3+T4+T5 stack).
//   - 512 thr / 8 waves (2Mx4N), BK=64, 128KiB dynamic LDS: 2 slots x
//     {A-k0, A-k1, B-k0, B-k1} regions of [256 rows][32 k] bf16.
//   - XOR swizzle on 16B granules: col ^ ((row>>1)&3)  (both-sides rule:
//     pre-swizzled global source + swizzled ds_read addr; linear LDS dest).
//   - stage stream 3 regions ahead; one s_waitcnt vmcnt(6) per K-tile
//     (vmcnt(0) only on the last tile); raw s_barrier (no vmcnt drain).
//   - setprio(1) around each 16-MFMA cluster.
//   - tanh-form GELU (<=5e-4 abs dev) instead of erff.

#define E_ 8
#define C_ 2048
#define D_ 2048
#define F_ 8192

typedef short bf16x8 __attribute__((ext_vector_type(8)));
typedef float f32x4  __attribute__((ext_vector_type(4)));

__device__ inline unsigned short f2bf(float f) {
    unsigned u = __float_as_uint(f);
    u += 0x7fffu + ((u >> 16) & 1u);
    return (unsigned short)(u >> 16);
}

__device__ inline float gelu_fast(float x) {
    float z = 0.7978845608028654f * (x + 0.044715f * x * x * x);
    float e = __expf(-2.0f * fabsf(z));
    float t = (1.0f - e) / (1.0f + e);
    t = copysignf(t, z);
    return 0.5f * x * (1.0f + t);
}

__device__ inline void gload_lds16(const void* g, void* l) {
    __builtin_amdgcn_global_load_lds(
        (const __attribute__((address_space(1))) void*)g,
        (__attribute__((address_space(3))) void*)l, 16, 0, 0);
}

// ---------------------------------------------------------------- cvt x ----
__global__ __launch_bounds__(256) void cvt_kernel(
    const float* __restrict__ in, unsigned short* __restrict__ out, long n4)
{
    long i = (long)blockIdx.x * 256 + threadIdx.x;
    if (i >= n4) return;
    float4 v = ((const float4*)in)[i];
    union { unsigned short u[4]; uint2 q; } r;
    r.u[0] = f2bf(v.x); r.u[1] = f2bf(v.y); r.u[2] = f2bf(v.z); r.u[3] = f2bf(v.w);
    ((uint2*)out)[i] = r.q;
}

// --------------------------------------------- transpose + cvt (weights) ----
__global__ __launch_bounds__(256) void transpose_cvt(
    const float* __restrict__ in, unsigned short* __restrict__ out,
    int R, int Cc, int RT, int CT)
{
    __shared__ float lds[64][65];
    int bx = blockIdx.x;
    int e  = bx / (RT * CT);
    int rem = bx % (RT * CT);
    int rt = rem / CT, ct = rem % CT;
    const float* ine = in + (long)e * R * Cc;
    unsigned short* oute = out + (long)e * R * Cc;
    long r0 = (long)rt * 64, c0 = (long)ct * 64;
    int t = threadIdx.x;

    int lr = t >> 4, lc = t & 15;
#pragma unroll
    for (int ii = 0; ii < 4; ++ii) {
        int r = lr + ii * 16;
        float4 v = *(const float4*)(ine + (r0 + r) * Cc + c0 + lc * 4);
        lds[r][lc * 4 + 0] = v.x; lds[r][lc * 4 + 1] = v.y;
        lds[r][lc * 4 + 2] = v.z; lds[r][lc * 4 + 3] = v.w;
    }
    __syncthreads();

    int nl = t >> 3, kv = t & 7;
#pragma unroll
    for (int ii = 0; ii < 2; ++ii) {
        int n = nl + ii * 32;
        union { unsigned short u[8]; uint4 q; } r;
#pragma unroll
        for (int j = 0; j < 8; ++j) r.u[j] = f2bf(lds[kv * 8 + j][n]);
        *(uint4*)(oute + (c0 + n) * R + r0 + kv * 8) = r.q;
    }
}

// ----------------------------------------------------------- 8-phase GEMM ----
// C[e][M][N] = A[e][M][K] * Bt[e][N][K]^T (+bias) (opt GELU).
// Region byte offsets within a 64KB slot:
#define REG_A0 0
#define REG_A1 16384
#define REG_B0 32768
#define REG_B1 49152
#define SLOT_B 65536

#define MFMA16(d, a, b) d = __builtin_amdgcn_mfma_f32_16x16x32_bf16(a, b, d, 0, 0, 0)

template <bool GELU, bool OUT_BF16>
__global__ __launch_bounds__(512, 2) void gemm8p(
    const unsigned short* __restrict__ A,
    const unsigned short* __restrict__ Bt,
    const float* __restrict__ bias,
    void* __restrict__ Cout,
    int M, int N, int K,
    long strideAe, long strideBe, long strideCe, int biasStride)
{
    extern __shared__ char ldsb[];   // 131072 bytes

    constexpr int BM = 256, BN = 256, BK = 64;
    int MT = M / BM, NT = N / BN;
    int nwg = gridDim.x;
    int bid = blockIdx.x;
    // bijective XCD swizzle (grids here are multiples of 8)
    int tile = (nwg % 8 == 0) ? (bid % 8) * (nwg / 8) + bid / 8 : bid;
    int e   = tile / (MT * NT);
    int rem = tile % (MT * NT);
    int mt = rem / NT, nt = rem % NT;

    const unsigned short* Ae = A  + (long)e * strideAe + (long)mt * BM * K;
    const unsigned short* Be = Bt + (long)e * strideBe + (long)nt * BN * K;

    int tid = threadIdx.x, lane = tid & 63, wid = tid >> 6;
    int wr = wid >> 2, wc = wid & 3;       // 2 (M) x 4 (N) wave grid; wave out: 128x64

    // stage one region (256 rows x 32 k of one matrix) = 16KB = 2 gload_lds/thread.
    // LDS dest linear in granule id; global source pre-swizzled col^((row>>1)&3).
    auto stage_region = [&](const unsigned short* base, int ktile, int kreg, int dstByte) {
        long k0 = (long)ktile * BK + kreg * 32;
#pragma unroll
        for (int i = 0; i < 2; ++i) {
            int g   = wid * 128 + i * 64 + lane;   // 0..1023 granules
            int row = g >> 2, col = g & 3;
            int sw  = col ^ ((row >> 1) & 3);
            gload_lds16(base + (long)row * K + k0 + sw * 8, ldsb + dstByte + g * 16);
        }
    };

    f32x4 acc[8][4] = {};
    int KT = K / BK;

    int rbaseA = wr * 128 + (lane & 15);
    int rbaseB = wc * 64  + (lane & 15);
    int kq = lane >> 4;

    // prologue: K-tile0 (slot0, all 4 regions) + K-tile1 (slot1: A0,B0,A1)
    stage_region(Ae, 0, 0, REG_A0);
    stage_region(Be, 0, 0, REG_B0);
    stage_region(Ae, 0, 1, REG_A1);
    stage_region(Be, 0, 1, REG_B1);
    stage_region(Ae, 1, 0, SLOT_B + REG_A0);
    stage_region(Be, 1, 0, SLOT_B + REG_B0);
    stage_region(Ae, 1, 1, SLOT_B + REG_A1);

    for (int T = 0; T < KT; ++T) {
        int so = (T & 1) * SLOT_B;

        // ---- checkpoint: K-tile T fully landed; 3 regions (6 loads) may fly
        if (T == KT - 1) asm volatile("s_waitcnt vmcnt(0)" ::: "memory");
        else             asm volatile("s_waitcnt vmcnt(6)" ::: "memory");
        __builtin_amdgcn_sched_barrier(0);
        __builtin_amdgcn_s_barrier();
        __builtin_amdgcn_sched_barrier(0);

        // ---- phase 0: read ks0 frags; stage B1(T+1) [other slot]; MFMA ks0 x n{0,1}
        bf16x8 a0[8], b0[4];
#pragma unroll
        for (int m = 0; m < 8; ++m) {
            int row = rbaseA + m * 16;
            a0[m] = *(const bf16x8*)(ldsb + so + REG_A0 + row * 64 + ((kq ^ ((row >> 1) & 3)) << 4));
        }
#pragma unroll
        for (int n = 0; n < 4; ++n) {
            int row = rbaseB + n * 16;
            b0[n] = *(const bf16x8*)(ldsb + so + REG_B0 + row * 64 + ((kq ^ ((row >> 1) & 3)) << 4));
        }
        if (T + 1 < KT) stage_region(Be, T + 1, 1, (so ^ SLOT_B) + REG_B1);
        __builtin_amdgcn_s_barrier();
        __builtin_amdgcn_s_setprio(1);
#pragma unroll
        for (int m = 0; m < 8; ++m) { MFMA16(acc[m][0], a0[m], b0[0]); MFMA16(acc[m][1], a0[m], b0[1]); }
        __builtin_amdgcn_s_setprio(0);
        __builtin_amdgcn_s_barrier();

        // ---- phase 1: stage A0(T+2) [this slot]; MFMA ks0 x n{2,3}
        if (T + 2 < KT) stage_region(Ae, T + 2, 0, so + REG_A0);
        __builtin_amdgcn_s_barrier();
        __builtin_amdgcn_s_setprio(1);
#pragma unroll
        for (int m = 0; m < 8; ++m) { MFMA16(acc[m][2], a0[m], b0[2]); MFMA16(acc[m][3], a0[m], b0[3]); }
        __builtin_amdgcn_s_setprio(0);
        __builtin_amdgcn_s_barrier();

        // ---- phase 2: read ks1 frags; stage B0(T+2); MFMA ks1 x n{0,1}
        bf16x8 a1[8], b1[4];
#pragma unroll
        for (int m = 0; m < 8; ++m) {
            int row = rbaseA + m * 16;
            a1[m] = *(const bf16x8*)(ldsb + so + REG_A1 + row * 64 + ((kq ^ ((row >> 1) & 3)) << 4));
        }
#pragma unroll
        for (int n = 0; n < 4; ++n) {
            int row = rbaseB + n * 16;
            b1[n] = *(const bf16x8*)(ldsb + so + REG_B1 + row * 64 + ((kq ^ ((row >> 1) & 3)) << 4));
        }
        if (T + 2 < KT) stage_region(Be, T + 2, 0, so + REG_B0);
        __builtin_amdgcn_s_barrier();
        __builtin_amdgcn_s_setprio(1);
#pragma unroll
        for (int m = 0; m < 8; ++m) { MFMA16(acc[m][0], a1[m], b1[0]); MFMA16(acc[m][1], a1[m], b1[1]); }
        __builtin_amdgcn_s_setprio(0);
        __builtin_amdgcn_s_barrier();

        // ---- phase 3: stage A1(T+2); MFMA ks1 x n{2,3}
        if (T + 2 < KT) stage_region(Ae, T + 2, 1, so + REG_A1);
        __builtin_amdgcn_s_barrier();
        __builtin_amdgcn_s_setprio(1);
#pragma unroll
        for (int m = 0; m < 8; ++m) { MFMA16(acc[m][2], a1[m], b1[2]); MFMA16(acc[m][3], a1[m], b1[3]); }
        __builtin_amdgcn_s_setprio(0);
        __builtin_amdgcn_s_barrier();
    }

    // ---- epilogue: C/D layout col=lane&15, row=(lane>>4)*4+j
    const float* be = bias + (long)e * biasStride + nt * BN;
    long cBase = (long)e * strideCe + ((long)mt * BM) * N + (long)nt * BN;
#pragma unroll
    for (int m = 0; m < 8; ++m) {
#pragma unroll
        for (int n = 0; n < 4; ++n) {
            int col = wc * 64 + n * 16 + (lane & 15);
            float bv = be[col];
#pragma unroll
            for (int j = 0; j < 4; ++j) {
                int row = wr * 128 + m * 16 + (lane >> 4) * 4 + j;
                float v = acc[m][n][j] + bv;
                if (GELU) v = gelu_fast(v);
                long idx = cBase + (long)row * N + col;
                if (OUT_BF16) ((unsigned short*)Cout)[idx] = f2bf(v);
                else          ((float*)Cout)[idx] = v;
            }
        }
    }
}

// ------------------------------------------------------------------ host ----
extern "C" void kernel_launch(void* const* d_in, const int* in_sizes, int n_in,
                              void* d_out, int out_size, void* d_ws, size_t ws_size,
                              hipStream_t stream)
{
    const float* x  = (const float*)d_in[0];
    const float* w1 = (const float*)d_in[1];
    const float* b1 = (const float*)d_in[2];
    const float* w2 = (const float*)d_in[3];
    const float* b2 = (const float*)d_in[4];
    float* out = (float*)d_out;

    (void)hipFuncSetAttribute((const void*)gemm8p<true, true>,
                              hipFuncAttributeMaxDynamicSharedMemorySize, 131072);
    (void)hipFuncSetAttribute((const void*)gemm8p<false, false>,
                              hipFuncAttributeMaxDynamicSharedMemorySize, 131072);

    const long CD = (long)C_ * D_;
    const long DF = (long)D_ * F_;
    const long CF = (long)C_ * F_;
    const long perExpertElems = CD + 2 * DF + CF;
    long ceMax = (long)(ws_size / ((size_t)perExpertElems * 2));
    int CE = (int)(ceMax < 1 ? 1 : (ceMax > E_ ? E_ : ceMax));

    unsigned short* xb  = (unsigned short*)d_ws;
    unsigned short* w1t = xb  + (long)CE * CD;   // [e][F][D]
    unsigned short* w2t = w1t + (long)CE * DF;   // [e][D][F]
    unsigned short* h   = w2t + (long)CE * DF;   // [e][C][F]

    for (int e0 = 0; e0 < E_; e0 += CE) {
        int ce = (E_ - e0) < CE ? (E_ - e0) : CE;

        long n4 = (long)ce * CD / 4;
        cvt_kernel<<<(int)((n4 + 255) / 256), 256, 0, stream>>>(
            x + (long)e0 * CD, xb, n4);

        transpose_cvt<<<ce * (D_ / 64) * (F_ / 64), 256, 0, stream>>>(
            w1 + (long)e0 * DF, w1t, D_, F_, D_ / 64, F_ / 64);

        transpose_cvt<<<ce * (F_ / 64) * (D_ / 64), 256, 0, stream>>>(
            w2 + (long)e0 * DF, w2t, F_, D_, F_ / 64, D_ / 64);

        gemm8p<true, true><<<ce * (C_ / 256) * (F_ / 256), 512, 131072, stream>>>(
            xb, w1t, b1 + (long)e0 * F_, (void*)h,
            C_, F_, D_, CD, DF, CF, F_);

        gemm8p<false, false><<<ce * (C_ / 256) * (D_ / 256), 512, 131072, stream>>>(
            h, w2t, b2 + (long)e0 * D_, (void*)(out + (long)e0 * CD),
            C_, D_, F_, CF, DF, CD, D_);
    }
}

// Round 4
// 1475.546 us; speedup vs baseline: 1.4189x; 1.0347x over previous
//
#include <hip/hip_runtime.h>
#include <hip/hip_bf16.h>

// Grouped experts FFN. E=8, C=2048, D=2048, F=8192.
// y[e] = GELU(x[e] @ W1[e] + b1[e]) @ W2[e] + b2[e]
// R4: 256x256 8-phase GEMM + (1) GROUP_N=4 L2 rasterization,
//     (2) quadrant-balanced phases w/ explicit lgkmcnt(0)+sched_barrier,
//     (3) rebalanced stage schedule (P0:B1(T+1), P2:B0(T+2), P3:A0+A1(T+2)).

#define E_ 8
#define C_ 2048
#define D_ 2048
#define F_ 8192

typedef short bf16x8 __attribute__((ext_vector_type(8)));
typedef float f32x4  __attribute__((ext_vector_type(4)));

__device__ inline unsigned short f2bf(float f) {
    unsigned u = __float_as_uint(f);
    u += 0x7fffu + ((u >> 16) & 1u);
    return (unsigned short)(u >> 16);
}

__device__ inline float gelu_fast(float x) {
    float z = 0.7978845608028654f * (x + 0.044715f * x * x * x);
    float e = __expf(-2.0f * fabsf(z));
    float t = (1.0f - e) / (1.0f + e);
    t = copysignf(t, z);
    return 0.5f * x * (1.0f + t);
}

__device__ inline void gload_lds16(const void* g, void* l) {
    __builtin_amdgcn_global_load_lds(
        (const __attribute__((address_space(1))) void*)g,
        (__attribute__((address_space(3))) void*)l, 16, 0, 0);
}

// ---------------------------------------------------------------- cvt x ----
__global__ __launch_bounds__(256) void cvt_kernel(
    const float* __restrict__ in, unsigned short* __restrict__ out, long n4)
{
    long i = (long)blockIdx.x * 256 + threadIdx.x;
    if (i >= n4) return;
    float4 v = ((const float4*)in)[i];
    union { unsigned short u[4]; uint2 q; } r;
    r.u[0] = f2bf(v.x); r.u[1] = f2bf(v.y); r.u[2] = f2bf(v.z); r.u[3] = f2bf(v.w);
    ((uint2*)out)[i] = r.q;
}

// --------------------------------------------- transpose + cvt (weights) ----
__global__ __launch_bounds__(256) void transpose_cvt(
    const float* __restrict__ in, unsigned short* __restrict__ out,
    int R, int Cc, int RT, int CT)
{
    __shared__ float lds[64][65];
    int bx = blockIdx.x;
    int e  = bx / (RT * CT);
    int rem = bx % (RT * CT);
    int rt = rem / CT, ct = rem % CT;
    const float* ine = in + (long)e * R * Cc;
    unsigned short* oute = out + (long)e * R * Cc;
    long r0 = (long)rt * 64, c0 = (long)ct * 64;
    int t = threadIdx.x;

    int lr = t >> 4, lc = t & 15;
#pragma unroll
    for (int ii = 0; ii < 4; ++ii) {
        int r = lr + ii * 16;
        float4 v = *(const float4*)(ine + (r0 + r) * Cc + c0 + lc * 4);
        lds[r][lc * 4 + 0] = v.x; lds[r][lc * 4 + 1] = v.y;
        lds[r][lc * 4 + 2] = v.z; lds[r][lc * 4 + 3] = v.w;
    }
    __syncthreads();

    int nl = t >> 3, kv = t & 7;
#pragma unroll
    for (int ii = 0; ii < 2; ++ii) {
        int n = nl + ii * 32;
        union { unsigned short u[8]; uint4 q; } r;
#pragma unroll
        for (int j = 0; j < 8; ++j) r.u[j] = f2bf(lds[kv * 8 + j][n]);
        *(uint4*)(oute + (c0 + n) * R + r0 + kv * 8) = r.q;
    }
}

// ----------------------------------------------------------- 8-phase GEMM ----
#define REG_A0 0
#define REG_A1 16384
#define REG_B0 32768
#define REG_B1 49152
#define SLOT_B 65536

#define MFMA16(d, a, b) d = __builtin_amdgcn_mfma_f32_16x16x32_bf16(a, b, d, 0, 0, 0)
#define LGKM0_FENCE() do { \
    asm volatile("s_waitcnt lgkmcnt(0)" ::: "memory"); \
    __builtin_amdgcn_sched_barrier(0); } while (0)

template <bool GELU, bool OUT_BF16>
__global__ __launch_bounds__(512, 2) void gemm8p(
    const unsigned short* __restrict__ A,
    const unsigned short* __restrict__ Bt,
    const float* __restrict__ bias,
    void* __restrict__ Cout,
    int M, int N, int K,
    long strideAe, long strideBe, long strideCe, int biasStride)
{
    extern __shared__ char ldsb[];   // 131072 bytes

    constexpr int BM = 256, BN = 256, BK = 64, GRP = 4;
    int MT = M / BM, NT = N / BN;
    int per = MT * NT;
    int nwg = gridDim.x;
    int bid = blockIdx.x;
    // XCD chunking: XCD x gets a contiguous within-grid chunk
    int tile = (nwg % 8 == 0) ? (bid & 7) * (nwg >> 3) + (bid >> 3) : bid;
    int e = tile / per, s = tile % per;
    // GROUP_N rasterization: (nt-group of GRP) major, mt middle, nt-in-group minor
    int ng  = s / (MT * GRP);
    int r2  = s % (MT * GRP);
    int mt  = r2 >> 2;               // r2 / GRP
    int nt  = ng * GRP + (r2 & 3);   // r2 % GRP

    const unsigned short* Ae = A  + (long)e * strideAe + (long)mt * BM * K;
    const unsigned short* Be = Bt + (long)e * strideBe + (long)nt * BN * K;

    int tid = threadIdx.x, lane = tid & 63, wid = tid >> 6;
    int wr = wid >> 2, wc = wid & 3;   // 2(M) x 4(N) waves; wave out 128x64

    // hoisted per-thread staging offsets (2 granules/region/thread)
    int g0 = wid * 128 + lane, g1 = g0 + 64;
    long sOff0, sOff1; int sDst0, sDst1;
    { int row = g0 >> 2, col = g0 & 3, sw = col ^ ((row >> 1) & 3);
      sOff0 = (long)row * K + sw * 8; sDst0 = g0 * 16; }
    { int row = g1 >> 2, col = g1 & 3, sw = col ^ ((row >> 1) & 3);
      sOff1 = (long)row * K + sw * 8; sDst1 = g1 * 16; }

    auto stage_region = [&](const unsigned short* base, int ktile, int kreg, int dstByte) {
        long k0 = (long)ktile * BK + kreg * 32;
        gload_lds16(base + sOff0 + k0, ldsb + dstByte + sDst0);
        gload_lds16(base + sOff1 + k0, ldsb + dstByte + sDst1);
    };

    f32x4 acc[8][4] = {};
    int KT = K / BK;

    int rbaseA = wr * 128 + (lane & 15);
    int rbaseB = wc * 64  + (lane & 15);
    int kq = lane >> 4;

    auto rdA = [&](int so, int ks, int m) -> bf16x8 {
        int row = rbaseA + m * 16;
        return *(const bf16x8*)(ldsb + so + (ks ? REG_A1 : REG_A0)
                                + row * 64 + ((kq ^ ((row >> 1) & 3)) << 4));
    };
    auto rdB = [&](int so, int ks, int n) -> bf16x8 {
        int row = rbaseB + n * 16;
        return *(const bf16x8*)(ldsb + so + (ks ? REG_B1 : REG_B0)
                                + row * 64 + ((kq ^ ((row >> 1) & 3)) << 4));
    };

    // prologue: tile0 all 4 regions, tile1 {A0,B0,A1} (B1(1) staged at T=0.P0)
    stage_region(Ae, 0, 0, REG_A0);
    stage_region(Be, 0, 0, REG_B0);
    stage_region(Ae, 0, 1, REG_A1);
    stage_region(Be, 0, 1, REG_B1);
    stage_region(Ae, 1, 0, SLOT_B + REG_A0);
    stage_region(Be, 1, 0, SLOT_B + REG_B0);
    stage_region(Ae, 1, 1, SLOT_B + REG_A1);

    bf16x8 a[8][2], b[4][2];

    for (int T = 0; T < KT; ++T) {
        int so = (T & 1) * SLOT_B;

        // ---- checkpoint: tile T fully landed; ≤6 loads (3 regions) in flight
        if (T == KT - 1) asm volatile("s_waitcnt vmcnt(0)" ::: "memory");
        else             asm volatile("s_waitcnt vmcnt(6)" ::: "memory");
        __builtin_amdgcn_sched_barrier(0);
        __builtin_amdgcn_s_barrier();
        __builtin_amdgcn_sched_barrier(0);

        // ---- P0: reads a[0..3][*], b[0..1][*] (12); stage B1(T+1); Q00
        #pragma unroll
        for (int m = 0; m < 4; ++m) { a[m][0] = rdA(so, 0, m); a[m][1] = rdA(so, 1, m); }
        #pragma unroll
        for (int n = 0; n < 2; ++n) { b[n][0] = rdB(so, 0, n); b[n][1] = rdB(so, 1, n); }
        if (T + 1 < KT) stage_region(Be, T + 1, 1, (so ^ SLOT_B) + REG_B1);
        __builtin_amdgcn_s_barrier();
        LGKM0_FENCE();
        __builtin_amdgcn_s_setprio(1);
        #pragma unroll
        for (int m = 0; m < 4; ++m)
            #pragma unroll
            for (int n = 0; n < 2; ++n) {
                MFMA16(acc[m][n], a[m][0], b[n][0]);
                MFMA16(acc[m][n], a[m][1], b[n][1]);
            }
        __builtin_amdgcn_s_setprio(0);
        __builtin_amdgcn_s_barrier();

        // ---- P1: reads b[2..3][*] (4); Q01
        #pragma unroll
        for (int n = 2; n < 4; ++n) { b[n][0] = rdB(so, 0, n); b[n][1] = rdB(so, 1, n); }
        __builtin_amdgcn_s_barrier();
        LGKM0_FENCE();
        __builtin_amdgcn_s_setprio(1);
        #pragma unroll
        for (int m = 0; m < 4; ++m)
            #pragma unroll
            for (int n = 2; n < 4; ++n) {
                MFMA16(acc[m][n], a[m][0], b[n][0]);
                MFMA16(acc[m][n], a[m][1], b[n][1]);
            }
        __builtin_amdgcn_s_setprio(0);
        __builtin_amdgcn_s_barrier();

        // ---- P2: reads a[4..7][*] (8); stage B0(T+2); Q10
        #pragma unroll
        for (int m = 4; m < 8; ++m) { a[m][0] = rdA(so, 0, m); a[m][1] = rdA(so, 1, m); }
        if (T + 2 < KT) stage_region(Be, T + 2, 0, so + REG_B0);
        __builtin_amdgcn_s_barrier();
        LGKM0_FENCE();
        __builtin_amdgcn_s_setprio(1);
        #pragma unroll
        for (int m = 4; m < 8; ++m)
            #pragma unroll
            for (int n = 0; n < 2; ++n) {
                MFMA16(acc[m][n], a[m][0], b[n][0]);
                MFMA16(acc[m][n], a[m][1], b[n][1]);
            }
        __builtin_amdgcn_s_setprio(0);
        __builtin_amdgcn_s_barrier();

        // ---- P3: stage A0(T+2), A1(T+2); Q11
        if (T + 2 < KT) {
            stage_region(Ae, T + 2, 0, so + REG_A0);
            stage_region(Ae, T + 2, 1, so + REG_A1);
        }
        __builtin_amdgcn_s_barrier();
        __builtin_amdgcn_s_setprio(1);
        #pragma unroll
        for (int m = 4; m < 8; ++m)
            #pragma unroll
            for (int n = 2; n < 4; ++n) {
                MFMA16(acc[m][n], a[m][0], b[n][0]);
                MFMA16(acc[m][n], a[m][1], b[n][1]);
            }
        __builtin_amdgcn_s_setprio(0);
        __builtin_amdgcn_s_barrier();
    }

    // ---- epilogue: C/D layout col=lane&15, row=(lane>>4)*4+j
    const float* be = bias + (long)e * biasStride + nt * BN;
    long cBase = (long)e * strideCe + ((long)mt * BM) * N + (long)nt * BN;
#pragma unroll
    for (int m = 0; m < 8; ++m) {
#pragma unroll
        for (int n = 0; n < 4; ++n) {
            int col = wc * 64 + n * 16 + (lane & 15);
            float bv = be[col];
#pragma unroll
            for (int j = 0; j < 4; ++j) {
                int row = wr * 128 + m * 16 + (lane >> 4) * 4 + j;
                float v = acc[m][n][j] + bv;
                if (GELU) v = gelu_fast(v);
                long idx = cBase + (long)row * N + col;
                if (OUT_BF16) ((unsigned short*)Cout)[idx] = f2bf(v);
                else          ((float*)Cout)[idx] = v;
            }
        }
    }
}

// ------------------------------------------------------------------ host ----
extern "C" void kernel_launch(void* const* d_in, const int* in_sizes, int n_in,
                              void* d_out, int out_size, void* d_ws, size_t ws_size,
                              hipStream_t stream)
{
    const float* x  = (const float*)d_in[0];
    const float* w1 = (const float*)d_in[1];
    const float* b1 = (const float*)d_in[2];
    const float* w2 = (const float*)d_in[3];
    const float* b2 = (const float*)d_in[4];
    float* out = (float*)d_out;

    (void)hipFuncSetAttribute((const void*)gemm8p<true, true>,
                              hipFuncAttributeMaxDynamicSharedMemorySize, 131072);
    (void)hipFuncSetAttribute((const void*)gemm8p<false, false>,
                              hipFuncAttributeMaxDynamicSharedMemorySize, 131072);

    const long CD = (long)C_ * D_;
    const long DF = (long)D_ * F_;
    const long CF = (long)C_ * F_;
    const long perExpertElems = CD + 2 * DF + CF;
    long ceMax = (long)(ws_size / ((size_t)perExpertElems * 2));
    int CE = (int)(ceMax < 1 ? 1 : (ceMax > E_ ? E_ : ceMax));

    unsigned short* xb  = (unsigned short*)d_ws;
    unsigned short* w1t = xb  + (long)CE * CD;   // [e][F][D]
    unsigned short* w2t = w1t + (long)CE * DF;   // [e][D][F]
    unsigned short* h   = w2t + (long)CE * DF;   // [e][C][F]

    for (int e0 = 0; e0 < E_; e0 += CE) {
        int ce = (E_ - e0) < CE ? (E_ - e0) : CE;

        long n4 = (long)ce * CD / 4;
        cvt_kernel<<<(int)((n4 + 255) / 256), 256, 0, stream>>>(
            x + (long)e0 * CD, xb, n4);

        transpose_cvt<<<ce * (D_ / 64) * (F_ / 64), 256, 0, stream>>>(
            w1 + (long)e0 * DF, w1t, D_, F_, D_ / 64, F_ / 64);

        transpose_cvt<<<ce * (F_ / 64) * (D_ / 64), 256, 0, stream>>>(
            w2 + (long)e0 * DF, w2t, F_, D_, F_ / 64, D_ / 64);

        gemm8p<true, true><<<ce * (C_ / 256) * (F_ / 256), 512, 131072, stream>>>(
            xb, w1t, b1 + (long)e0 * F_, (void*)h,
            C_, F_, D_, CD, DF, CF, F_);

        gemm8p<false, false><<<ce * (C_ / 256) * (D_ / 256), 512, 131072, stream>>>(
            h, w2t, b2 + (long)e0 * D_, (void*)(out + (long)e0 * CD),
            C_, D_, F_, CF, DF, CD, D_);
    }
}